// Round 4
// baseline (90.364 us; speedup 1.0000x reference)
//
#include <hip/hip_runtime.h>

// RotationalConv2D, MFMA + pipelined (R4).
// vs R3: (1) W hoisted to registers (13 bf16 B-fragments/lane, converted once in
// the prologue -> no global traffic in the chunk loop); (2) double-buffered
// A-panel -> 1 barrier/chunk instead of 2; (3) chunk loop fully unrolled so
// MFMA(ch) overlaps blend(ch+1) within the same barrier interval.

#define KS     5
#define TILE   8
#define NPIX   64
#define TW     (TILE + KS - 1)     // 12
#define CPAD   20                  // padded channel stride (floats)
#define C_IN   16
#define F_OUT  32
#define H_IN   128
#define W_IN   128
#define HO     124
#define WO     124
#define NBATCH 4
#define EPSF   1e-7f
#define BLOCK  256
#define NCHUNK 7                   // ceil(25 taps / 4)
#define NKSTEP 13                  // ceil(400 / 32)
#define AROW   72                  // 64 K + 8 pad (bf16); 36 dwords == stride-1 bank profile
#define KW     400                 // K = 25*16

typedef __attribute__((ext_vector_type(8))) short  short8;   // 8 bf16 (4 VGPRs)
typedef __attribute__((ext_vector_type(4))) float  floatx4;

static __device__ __forceinline__ short f2bf(float f) {
    union { float f; unsigned u; } v; v.f = f;
    unsigned r = v.u + 0x7fffu + ((v.u >> 16) & 1u);   // RNE
    return (short)(r >> 16);
}

__global__ __launch_bounds__(BLOCK, 4) void rotconv_kernel(
    const float* __restrict__ in, const float* __restrict__ Wg,
    const float* __restrict__ bg, float* __restrict__ out)
{
    __shared__ float s_in[TW * TW * CPAD];      // 11.25 KB
    __shared__ float s_int[TW * (TW + 1)];      // 0.6 KB
    __shared__ short sA[2][NPIX * AROW];        // 2 x 9 KB (double buffer)

    const int tid  = threadIdx.x;
    const int bx = blockIdx.x, by = blockIdx.y, bimg = blockIdx.z;
    const int ox = bx * TILE, oy = by * TILE;

    const int p    = tid & 63;     // pixel index in 8x8 tile == lane
    const int wv   = tid >> 6;     // wave id 0..3
    const int lx   = p & 7, ly = p >> 3;
    const int col  = p & 15;       // MFMA lane&15
    const int quad = p >> 4;       // MFMA lane>>4
    const int nt   = wv >> 1;      // which 16 of F
    const int mt0  = (wv & 1) * 2; // M-tiles mt0, mt0+1

    // ---- hoist W: 13 bf16 B-fragments per lane, loaded/converted once ----
    short8 wfrag[NKSTEP];
    {
        const float* wrow = Wg + (size_t)(nt * 16 + col) * KW;
        #pragma unroll
        for (int s = 0; s < NKSTEP; ++s) {
            int kg = s * 32 + quad * 8;
            short8 bf = {0,0,0,0,0,0,0,0};
            if (kg + 8 <= KW) {                  // K>=400 rows are zero
                float4 a = *(const float4*)(wrow + kg);
                float4 b = *(const float4*)(wrow + kg + 4);
                bf = (short8){f2bf(a.x), f2bf(a.y), f2bf(a.z), f2bf(a.w),
                              f2bf(b.x), f2bf(b.y), f2bf(b.z), f2bf(b.w)};
            }
            wfrag[s] = bf;
        }
    }

    // ---- stage input tile (12x12x16) ----
    const float* inb = in + (size_t)bimg * (H_IN * W_IN * C_IN);
    for (int i = tid; i < TW * TW * (C_IN / 4); i += BLOCK) {
        int cv = i & 3;
        int pp = i >> 2;
        int x = pp % TW, y = pp / TW;
        int gy = oy + y, gx = ox + x;
        float4 v = make_float4(0.f, 0.f, 0.f, 0.f);
        if (gy < H_IN && gx < W_IN)
            v = *(const float4*)(inb + ((size_t)(gy * W_IN + gx) * C_IN) + 4 * cv);
        *(float4*)(&s_in[pp * CPAD + 4 * cv]) = v;
    }
    __syncthreads();

    // ---- intensity = channel sum ----
    for (int pp = tid; pp < TW * TW; pp += BLOCK) {
        const float* sp = &s_in[pp * CPAD];
        float s = 0.f;
        #pragma unroll
        for (int c = 0; c < C_IN; ++c) s += sp[c];
        s_int[(pp / TW) * (TW + 1) + (pp % TW)] = s;
    }
    __syncthreads();

    // ---- per-pixel angle (redundant across the 4 waves; cheap) ----
    float tot = EPSF, cr = 0.f, cc = 0.f;
    #pragma unroll
    for (int dy = 0; dy < KS; ++dy)
        #pragma unroll
        for (int dx = 0; dx < KS; ++dx) {
            float v = s_int[(ly + dy) * (TW + 1) + (lx + dx)];
            tot += v; cr += v * (float)dy; cc += v * (float)dx;
        }
    cr /= tot; cc /= tot;
    float ang = atan2f(cr - 2.0f, cc - 2.0f + EPSF);
    float si, co;
    sincosf(ang, &si, &co);
    const float scl = 1.0f / (1.0f + EPSF);
    float xoff = (4.0f - (co * 4.0f - si * 4.0f)) * 0.5f;
    float yoff = (4.0f - (si * 4.0f + co * 4.0f)) * 0.5f;

    floatx4 acc0, acc1;
    {
        float bv = bg[nt * 16 + col];  // bias pre-load into accumulator
        acc0 = (floatx4){bv, bv, bv, bv};
        acc1 = acc0;
    }

    #pragma unroll
    for (int ch = 0; ch < NCHUNK; ++ch) {
        // ---- blend: wave wv computes tap t = 4ch+wv for its 64 pixels ----
        int t = 4 * ch + wv;
        short8 alo = {0,0,0,0,0,0,0,0}, ahi = {0,0,0,0,0,0,0,0};
        if (t < KS * KS) {                       // wave-uniform branch
            int ky = t / KS, kx = t - KS * ky;
            float sx = (co * (float)kx - si * (float)ky + xoff) * scl;
            float sy = (si * (float)kx + co * (float)ky + yoff) * scl;
            float fx0 = floorf(sx), fy0 = floorf(sy);
            float wx = sx - fx0, wy = sy - fy0;
            int x0 = (int)fx0, y0 = (int)fy0;
            int x1 = x0 + 1, y1 = y0 + 1;
            float vx0 = (x0 >= 0 && x0 < KS) ? 1.f : 0.f;
            float vx1 = (x1 >= 0 && x1 < KS) ? 1.f : 0.f;
            float vy0 = (y0 >= 0 && y0 < KS) ? 1.f : 0.f;
            float vy1 = (y1 >= 0 && y1 < KS) ? 1.f : 0.f;
            float w00 = (1.f - wx) * (1.f - wy) * vx0 * vy0;
            float w01 = wx * (1.f - wy) * vx1 * vy0;
            float w10 = (1.f - wx) * wy * vx0 * vy1;
            float w11 = wx * wy * vx1 * vy1;
            int cx0 = min(max(x0, 0), KS - 1), cx1 = min(max(x1, 0), KS - 1);
            int cy0 = min(max(y0, 0), KS - 1), cy1 = min(max(y1, 0), KS - 1);
            const float* p00 = &s_in[((ly + cy0) * TW + (lx + cx0)) * CPAD];
            const float* p01 = &s_in[((ly + cy0) * TW + (lx + cx1)) * CPAD];
            const float* p10 = &s_in[((ly + cy1) * TW + (lx + cx0)) * CPAD];
            const float* p11 = &s_in[((ly + cy1) * TW + (lx + cx1)) * CPAD];
            float r[16];
            #pragma unroll
            for (int cv = 0; cv < 4; ++cv) {
                float4 a = *(const float4*)(p00 + 4 * cv);
                float4 b = *(const float4*)(p01 + 4 * cv);
                float4 c = *(const float4*)(p10 + 4 * cv);
                float4 d = *(const float4*)(p11 + 4 * cv);
                r[4*cv+0] = w00 * a.x + w01 * b.x + w10 * c.x + w11 * d.x;
                r[4*cv+1] = w00 * a.y + w01 * b.y + w10 * c.y + w11 * d.y;
                r[4*cv+2] = w00 * a.z + w01 * b.z + w10 * c.z + w11 * d.z;
                r[4*cv+3] = w00 * a.w + w01 * b.w + w10 * c.w + w11 * d.w;
            }
            alo = (short8){f2bf(r[0]), f2bf(r[1]), f2bf(r[2]), f2bf(r[3]),
                           f2bf(r[4]), f2bf(r[5]), f2bf(r[6]), f2bf(r[7])};
            ahi = (short8){f2bf(r[8]),  f2bf(r[9]),  f2bf(r[10]), f2bf(r[11]),
                           f2bf(r[12]), f2bf(r[13]), f2bf(r[14]), f2bf(r[15])};
        }
        short* buf = &sA[ch & 1][0];
        *(short8*)(&buf[p * AROW + wv * 16])     = alo;
        *(short8*)(&buf[p * AROW + wv * 16 + 8]) = ahi;
        __syncthreads();                          // A-panel ready (dbuf: no 2nd barrier)

        // ---- MFMA over this 64-K chunk (W already in registers) ----
        #pragma unroll
        for (int kk = 0; kk < 2; ++kk) {
            int s = ch * 2 + kk;
            if (s < NKSTEP) {
                short8 a0 = *(const short8*)(&buf[(16 * mt0 + col) * AROW + kk * 32 + quad * 8]);
                short8 a1 = *(const short8*)(&buf[(16 * mt0 + 16 + col) * AROW + kk * 32 + quad * 8]);
                acc0 = __builtin_amdgcn_mfma_f32_16x16x32_bf16(a0, wfrag[s], acc0, 0, 0, 0);
                acc1 = __builtin_amdgcn_mfma_f32_16x16x32_bf16(a1, wfrag[s], acc1, 0, 0, 0);
            }
        }
    }

    // ---- epilogue: C/D layout col=lane&15 (f), row=quad*4+reg (pixel) ----
    #pragma unroll
    for (int r = 0; r < 4; ++r) {
        int pix0 = 16 * mt0 + quad * 4 + r;
        int ho = oy + (pix0 >> 3), wo = ox + (pix0 & 7);
        if (ho < HO && wo < WO)
            out[(((size_t)bimg * HO + ho) * WO + wo) * F_OUT + nt * 16 + col] = acc0[r];
        int pix1 = pix0 + 16;
        ho = oy + (pix1 >> 3); wo = ox + (pix1 & 7);
        if (ho < HO && wo < WO)
            out[(((size_t)bimg * HO + ho) * WO + wo) * F_OUT + nt * 16 + col] = acc1[r];
    }
}

extern "C" void kernel_launch(void* const* d_in, const int* in_sizes, int n_in,
                              void* d_out, int out_size, void* d_ws, size_t ws_size,
                              hipStream_t stream) {
    const float* in = (const float*)d_in[0];
    const float* Wg = (const float*)d_in[1];
    const float* bg = (const float*)d_in[2];
    float* out      = (float*)d_out;
    dim3 grid((WO + TILE - 1) / TILE, (HO + TILE - 1) / TILE, NBATCH);
    rotconv_kernel<<<grid, dim3(BLOCK), 0, stream>>>(in, Wg, bg, out);
}

// Round 5
// 80.882 us; speedup vs baseline: 1.1172x; 1.1172x over previous
//
#include <hip/hip_runtime.h>

// RotationalConv2D R5: barrier-free hot loop.
// mfma_f32_32x32x16_bf16: one K-step = one tap's 16 channels; N=32 = all F.
// Each wave owns taps t = wv+4i (7/6/6/6 of 25): blends its tap for all 64 px,
// builds both 32-px A-fragments in-register via one lane^32 shuffle exchange
// (no LDS A-panel, no barriers), accumulates partial C; cross-wave LDS
// reduction at the end. W staged to LDS as bf16 once (aliased by the
// reduction buffer). 4 barriers total. No register hoist of W (R4 spilled).

#define KS     5
#define TILE   8
#define TW     (TILE + KS - 1)     // 12
#define CPAD   20                  // padded channel stride (floats)
#define C_IN   16
#define F_OUT  32
#define H_IN   128
#define W_IN   128
#define HO     124
#define WO     124
#define NBATCH 4
#define EPSF   1e-7f
#define BLOCK  256
#define NTAP   25
#define KW     400

typedef __attribute__((ext_vector_type(8)))  short short8;    // 8 bf16
typedef __attribute__((ext_vector_type(16))) float floatx16;  // 32x32 C/D frag

static __device__ __forceinline__ unsigned f2bfu(float f) {   // bf16 bits, RNE
    union { float f; unsigned u; } v; v.f = f;
    unsigned r = v.u + 0x7fffu + ((v.u >> 16) & 1u);
    return r >> 16;
}
static __device__ __forceinline__ unsigned pack2(float a, float b) {
    return f2bfu(a) | (f2bfu(b) << 16);
}

__global__ __launch_bounds__(BLOCK, 4) void rotconv_kernel(
    const float* __restrict__ in, const float* __restrict__ Wg,
    const float* __restrict__ bg, float* __restrict__ out)
{
    __shared__ float s_in[TW * TW * CPAD];            // 11.25 KB
    __shared__ float s_int[TW * (TW + 1)];            // 0.6 KB
    __shared__ union {
        short w[NTAP * 64 * 8];                       // 25.6 KB: B-frags, bf16
        float red[3 * 2048];                          // 24 KB: partial-C buffer
    } uW;

    const int tid  = threadIdx.x;
    const int bx = blockIdx.x, by = blockIdx.y, bimg = blockIdx.z;
    const int ox = bx * TILE, oy = by * TILE;
    const int p  = tid & 63;                           // lane == pixel in 8x8 tile
    const int wv = __builtin_amdgcn_readfirstlane(tid >> 6);
    const int lx = p & 7, ly = p >> 3;

    // ---- stage W -> LDS bf16, B-fragment layout: slot (t*64+l) holds
    //      W[f=l&31][k = t*16 + (l>>5)*8 + j], j=0..7 ----
    for (int i = tid; i < NTAP * 64; i += BLOCK) {
        int t = i >> 6, l = i & 63;
        const float* wp = Wg + (size_t)(l & 31) * KW + t * 16 + (l >> 5) * 8;
        float4 a = *(const float4*)(wp);
        float4 b = *(const float4*)(wp + 4);
        unsigned* d = (unsigned*)&uW.w[i * 8];
        d[0] = pack2(a.x, a.y); d[1] = pack2(a.z, a.w);
        d[2] = pack2(b.x, b.y); d[3] = pack2(b.z, b.w);
    }

    // ---- stage input tile (12x12x16) ----
    const float* inb = in + (size_t)bimg * (H_IN * W_IN * C_IN);
    for (int i = tid; i < TW * TW * (C_IN / 4); i += BLOCK) {
        int cv = i & 3;
        int pp = i >> 2;
        int x = pp % TW, y = pp / TW;
        int gy = oy + y, gx = ox + x;
        float4 v = make_float4(0.f, 0.f, 0.f, 0.f);
        if (gy < H_IN && gx < W_IN)
            v = *(const float4*)(inb + ((size_t)(gy * W_IN + gx) * C_IN) + 4 * cv);
        *(float4*)(&s_in[pp * CPAD + 4 * cv]) = v;
    }
    __syncthreads();                                   // (1)

    // ---- intensity = channel sum ----
    for (int pp = tid; pp < TW * TW; pp += BLOCK) {
        const float* sp = &s_in[pp * CPAD];
        float s = 0.f;
        #pragma unroll
        for (int c = 0; c < C_IN; ++c) s += sp[c];
        s_int[(pp / TW) * (TW + 1) + (pp % TW)] = s;
    }
    __syncthreads();                                   // (2)

    // ---- per-pixel angle (each lane: its own pixel; redundant across waves) ----
    float tot = EPSF, cr = 0.f, cc = 0.f;
    #pragma unroll
    for (int dy = 0; dy < KS; ++dy)
        #pragma unroll
        for (int dx = 0; dx < KS; ++dx) {
            float v = s_int[(ly + dy) * (TW + 1) + (lx + dx)];
            tot += v; cr += v * (float)dy; cc += v * (float)dx;
        }
    cr /= tot; cc /= tot;
    float ang = atan2f(cr - 2.0f, cc - 2.0f + EPSF);
    float si, co;
    sincosf(ang, &si, &co);
    const float scl = 1.0f / (1.0f + EPSF);
    float xoff = (4.0f - (co * 4.0f - si * 4.0f)) * 0.5f;
    float yoff = (4.0f - (si * 4.0f + co * 4.0f)) * 0.5f;

    floatx16 acc0 = {0}, acc1 = {0};                   // partial C; bias added at store

    // ---- hot loop: this wave's taps, NO barriers ----
    for (int i = 0; i < 7; ++i) {
        int t = wv + 4 * i;
        if (t < NTAP) {                                // wave-uniform
            int ky = t / KS, kx = t - KS * ky;
            float sx = (co * (float)kx - si * (float)ky + xoff) * scl;
            float sy = (si * (float)kx + co * (float)ky + yoff) * scl;
            float fx0 = floorf(sx), fy0 = floorf(sy);
            float wx = sx - fx0, wy = sy - fy0;
            int x0 = (int)fx0, y0 = (int)fy0;
            int x1 = x0 + 1, y1 = y0 + 1;
            float vx0 = (x0 >= 0 && x0 < KS) ? 1.f : 0.f;
            float vx1 = (x1 >= 0 && x1 < KS) ? 1.f : 0.f;
            float vy0 = (y0 >= 0 && y0 < KS) ? 1.f : 0.f;
            float vy1 = (y1 >= 0 && y1 < KS) ? 1.f : 0.f;
            float w00 = (1.f - wx) * (1.f - wy) * vx0 * vy0;
            float w01 = wx * (1.f - wy) * vx1 * vy0;
            float w10 = (1.f - wx) * wy * vx0 * vy1;
            float w11 = wx * wy * vx1 * vy1;
            int cx0 = min(max(x0, 0), KS - 1), cx1 = min(max(x1, 0), KS - 1);
            int cy0 = min(max(y0, 0), KS - 1), cy1 = min(max(y1, 0), KS - 1);
            const float* p00 = &s_in[((ly + cy0) * TW + (lx + cx0)) * CPAD];
            const float* p01 = &s_in[((ly + cy0) * TW + (lx + cx1)) * CPAD];
            const float* p10 = &s_in[((ly + cy1) * TW + (lx + cx0)) * CPAD];
            const float* p11 = &s_in[((ly + cy1) * TW + (lx + cx1)) * CPAD];
            float r[16];
            #pragma unroll
            for (int cv = 0; cv < 4; ++cv) {
                float4 a = *(const float4*)(p00 + 4 * cv);
                float4 b = *(const float4*)(p01 + 4 * cv);
                float4 c = *(const float4*)(p10 + 4 * cv);
                float4 d = *(const float4*)(p11 + 4 * cv);
                r[4*cv+0] = w00 * a.x + w01 * b.x + w10 * c.x + w11 * d.x;
                r[4*cv+1] = w00 * a.y + w01 * b.y + w10 * c.y + w11 * d.y;
                r[4*cv+2] = w00 * a.z + w01 * b.z + w10 * c.z + w11 * d.z;
                r[4*cv+3] = w00 * a.w + w01 * b.w + w10 * c.w + w11 * d.w;
            }
            // pack: lo = ch 0-7, hi = ch 8-15 (4 dwords each)
            unsigned lo[4], hi[4];
            #pragma unroll
            for (int d = 0; d < 4; ++d) {
                lo[d] = pack2(r[2*d],     r[2*d + 1]);
                hi[d] = pack2(r[8 + 2*d], r[9 + 2*d]);
            }
            // lane^32 exchange: lower lanes send hi (partner needs ch8-15 of px<32),
            // upper lanes send lo (partner needs ch0-7 of px>=32)
            union { unsigned u[4]; short8 v; } a0, a1;
            #pragma unroll
            for (int d = 0; d < 4; ++d) {
                unsigned snd = (p < 32) ? hi[d] : lo[d];
                unsigned rcv = (unsigned)__shfl((int)snd, p ^ 32, 64);
                a0.u[d] = (p < 32) ? lo[d] : rcv;   // M-tile 0: px 0-31
                a1.u[d] = (p < 32) ? rcv : hi[d];   // M-tile 1: px 32-63
            }
            short8 bf = *(const short8*)(&uW.w[(t * 64 + p) * 8]);
            acc0 = __builtin_amdgcn_mfma_f32_32x32x16_bf16(a0.v, bf, acc0, 0, 0, 0);
            acc1 = __builtin_amdgcn_mfma_f32_32x32x16_bf16(a1.v, bf, acc1, 0, 0, 0);
        }
    }

    __syncthreads();                                   // (3) sW dead -> reuse as red
    if (wv > 0) {                                      // waves 1-3 spill partial C
        float* red = &uW.red[(wv - 1) * 2048];
        #pragma unroll
        for (int r = 0; r < 16; ++r) {
            red[r * 64 + p]         = acc0[r];         // slot s = r      (tile 0)
            red[(16 + r) * 64 + p]  = acc1[r];         // slot s = 16 + r (tile 1)
        }
    }
    __syncthreads();                                   // (4)

    if (wv == 0) {
        // C/D layout: n(F) = lane&31, row = (reg&3) + 8*(reg>>2) + 4*(lane>>5)
        float bias = bg[p & 31];
        #pragma unroll
        for (int T = 0; T < 2; ++T) {
            #pragma unroll
            for (int r = 0; r < 16; ++r) {
                int s = T * 16 + r;
                float v = (T == 0 ? acc0[r] : acc1[r])
                        + uW.red[s * 64 + p]
                        + uW.red[2048 + s * 64 + p]
                        + uW.red[4096 + s * 64 + p] + bias;
                int px = T * 32 + (r & 3) + 8 * (r >> 2) + 4 * (p >> 5);
                int ho = oy + (px >> 3), wo = ox + (px & 7);
                if (ho < HO && wo < WO)
                    out[(((size_t)bimg * HO + ho) * WO + wo) * F_OUT + (p & 31)] = v;
            }
        }
    }
}

extern "C" void kernel_launch(void* const* d_in, const int* in_sizes, int n_in,
                              void* d_out, int out_size, void* d_ws, size_t ws_size,
                              hipStream_t stream) {
    const float* in = (const float*)d_in[0];
    const float* Wg = (const float*)d_in[1];
    const float* bg = (const float*)d_in[2];
    float* out      = (float*)d_out;
    dim3 grid((WO + TILE - 1) / TILE, (HO + TILE - 1) / TILE, NBATCH);
    rotconv_kernel<<<grid, dim3(BLOCK), 0, stream>>>(in, Wg, bg, out);
}

// Round 6
// 77.060 us; speedup vs baseline: 1.1726x; 1.0496x over previous
//
#include <hip/hip_runtime.h>

// RotationalConv2D R6.
// vs R5: (1) no lane^32 shuffle — lane = (channel-half, pixel-in-32tile), wave =
// (tile, tap-parity); blend produces the 32x32x16 A-fragment directly (8 ch/lane).
// (2) one 16-VGPR accumulator per wave; 2-way parallel epilogue reduction.
// (3) cos/sin of atan2 computed algebraically (rsqrt) — no transcendentals.
// (4) intensity fused into input staging. Hot loop: straight-line, 13 taps,
// dead tap masked by zeroed weights.

#define KS     5
#define TILE   8
#define TW     (TILE + KS - 1)     // 12
#define CPAD   20                  // padded channel stride (floats)
#define C_IN   16
#define F_OUT  32
#define H_IN   128
#define W_IN   128
#define HO     124
#define WO     124
#define NBATCH 4
#define EPSF   1e-7f
#define BLOCK  256
#define NTAP   25
#define KW     400

typedef __attribute__((ext_vector_type(8)))  short short8;    // 8 bf16
typedef __attribute__((ext_vector_type(16))) float floatx16;  // 32x32 C/D frag

static __device__ __forceinline__ unsigned f2bfu(float f) {   // bf16 bits, RNE
    union { float f; unsigned u; } v; v.f = f;
    unsigned r = v.u + 0x7fffu + ((v.u >> 16) & 1u);
    return r >> 16;
}
static __device__ __forceinline__ unsigned pack2(float a, float b) {
    return f2bfu(a) | (f2bfu(b) << 16);
}

__global__ __launch_bounds__(BLOCK, 4) void rotconv_kernel(
    const float* __restrict__ in, const float* __restrict__ Wg,
    const float* __restrict__ bg, float* __restrict__ out)
{
    __shared__ float s_in[TW * TW * CPAD];            // 11.25 KB
    __shared__ float s_int[TW * (TW + 1)];            // 0.6 KB
    __shared__ union {
        short w[NTAP * 64 * 8];                       // 25.6 KB: B-frags (bf16)
        float red[2 * 1024];                          // 8 KB: partial-C (overlay)
    } uW;

    const int tid = threadIdx.x;
    const int bx = blockIdx.x, by = blockIdx.y, bimg = blockIdx.z;
    const int ox = bx * TILE, oy = by * TILE;
    const int p  = tid & 63;
    const int wv = __builtin_amdgcn_readfirstlane(tid >> 6);
    const int tile = wv >> 1;        // which 32-px M-tile
    const int par  = wv & 1;         // tap parity
    const int m32  = p & 31;         // pixel within tile
    const int half = p >> 5;         // channel half (0: ch0-7, 1: ch8-15)
    const int q    = tile * 32 + m32;
    const int lx = q & 7, ly = q >> 3;

    // ---- stage W -> LDS bf16 B-frags: slot (t*64+l) = W[f=l&31][t*16+(l>>5)*8+j] ----
    for (int i = tid; i < NTAP * 64; i += BLOCK) {
        int t = i >> 6, l = i & 63;
        const float* wp = Wg + (size_t)(l & 31) * KW + t * 16 + (l >> 5) * 8;
        float4 a = *(const float4*)(wp);
        float4 b = *(const float4*)(wp + 4);
        unsigned* d = (unsigned*)&uW.w[i * 8];
        d[0] = pack2(a.x, a.y); d[1] = pack2(a.z, a.w);
        d[2] = pack2(b.x, b.y); d[3] = pack2(b.z, b.w);
    }

    // ---- stage input tile + fused intensity (one lane per position) ----
    const float* inb = in + (size_t)bimg * (H_IN * W_IN * C_IN);
    if (tid < TW * TW) {
        int x = tid % TW, y = tid / TW;
        int gy = oy + y, gx = ox + x;
        float4 v0 = {0,0,0,0}, v1 = {0,0,0,0}, v2 = {0,0,0,0}, v3 = {0,0,0,0};
        if (gy < H_IN && gx < W_IN) {
            const float* g = inb + (size_t)(gy * W_IN + gx) * C_IN;
            v0 = *(const float4*)(g);      v1 = *(const float4*)(g + 4);
            v2 = *(const float4*)(g + 8);  v3 = *(const float4*)(g + 12);
        }
        float* d = &s_in[tid * CPAD];
        *(float4*)(d)      = v0; *(float4*)(d + 4)  = v1;
        *(float4*)(d + 8)  = v2; *(float4*)(d + 12) = v3;
        s_int[y * (TW + 1) + x] =
            (v0.x+v0.y+v0.z+v0.w) + (v1.x+v1.y+v1.z+v1.w) +
            (v2.x+v2.y+v2.z+v2.w) + (v3.x+v3.y+v3.z+v3.w);
    }
    __syncthreads();                                   // (1)

    // ---- centroid -> (co,si) for my pixel q, no transcendentals ----
    float tot = EPSF, cr = 0.f, cc = 0.f;
    #pragma unroll
    for (int dy = 0; dy < KS; ++dy)
        #pragma unroll
        for (int dx = 0; dx < KS; ++dx) {
            float v = s_int[(ly + dy) * (TW + 1) + (lx + dx)];
            tot += v; cr += v * (float)dy; cc += v * (float)dx;
        }
    cr /= tot; cc /= tot;
    float yv = cr - 2.0f;
    float xv = cc - 2.0f + EPSF;
    float rh = rsqrtf(fmaxf(xv * xv + yv * yv, 1e-30f));
    float co = xv * rh, si = yv * rh;                  // cos/sin of atan2(yv,xv)
    const float scl = 1.0f / (1.0f + EPSF);
    float xoff = (4.0f - (co * 4.0f - si * 4.0f)) * 0.5f;
    float yoff = (4.0f - (si * 4.0f + co * 4.0f)) * 0.5f;

    floatx16 acc = {0};                                 // bias added at store

    // ---- hot loop: taps t = 2i+par; no barriers, no shuffles ----
    for (int i = 0; i < 13; ++i) {
        int t = 2 * i + par;
        float live = (t < NTAP) ? 1.f : 0.f;            // odd waves: i=12 is dead
        int tt = min(t, NTAP - 1);
        int ky = tt / KS, kx = tt - KS * ky;
        float sx = (co * (float)kx - si * (float)ky + xoff) * scl;
        float sy = (si * (float)kx + co * (float)ky + yoff) * scl;
        float fx0 = floorf(sx), fy0 = floorf(sy);
        float wx = sx - fx0, wy = sy - fy0;
        int x0 = (int)fx0, y0 = (int)fy0;
        int x1 = x0 + 1, y1 = y0 + 1;
        float vx0 = (x0 >= 0 && x0 < KS) ? live : 0.f;
        float vx1 = (x1 >= 0 && x1 < KS) ? live : 0.f;
        float vy0 = (y0 >= 0 && y0 < KS) ? 1.f : 0.f;
        float vy1 = (y1 >= 0 && y1 < KS) ? 1.f : 0.f;
        float w00 = (1.f - wx) * (1.f - wy) * vx0 * vy0;
        float w01 = wx * (1.f - wy) * vx1 * vy0;
        float w10 = (1.f - wx) * wy * vx0 * vy1;
        float w11 = wx * wy * vx1 * vy1;
        int cx0 = min(max(x0, 0), KS - 1), cx1 = min(max(x1, 0), KS - 1);
        int cy0 = min(max(y0, 0), KS - 1), cy1 = min(max(y1, 0), KS - 1);
        const float* p00 = &s_in[((ly + cy0) * TW + (lx + cx0)) * CPAD + half * 8];
        const float* p01 = &s_in[((ly + cy0) * TW + (lx + cx1)) * CPAD + half * 8];
        const float* p10 = &s_in[((ly + cy1) * TW + (lx + cx0)) * CPAD + half * 8];
        const float* p11 = &s_in[((ly + cy1) * TW + (lx + cx1)) * CPAD + half * 8];
        float4 a0 = *(const float4*)(p00), a1 = *(const float4*)(p00 + 4);
        float4 b0 = *(const float4*)(p01), b1 = *(const float4*)(p01 + 4);
        float4 c0 = *(const float4*)(p10), c1 = *(const float4*)(p10 + 4);
        float4 d0 = *(const float4*)(p11), d1 = *(const float4*)(p11 + 4);
        float r0 = w00*a0.x + w01*b0.x + w10*c0.x + w11*d0.x;
        float r1 = w00*a0.y + w01*b0.y + w10*c0.y + w11*d0.y;
        float r2 = w00*a0.z + w01*b0.z + w10*c0.z + w11*d0.z;
        float r3 = w00*a0.w + w01*b0.w + w10*c0.w + w11*d0.w;
        float r4 = w00*a1.x + w01*b1.x + w10*c1.x + w11*d1.x;
        float r5 = w00*a1.y + w01*b1.y + w10*c1.y + w11*d1.y;
        float r6 = w00*a1.z + w01*b1.z + w10*c1.z + w11*d1.z;
        float r7 = w00*a1.w + w01*b1.w + w10*c1.w + w11*d1.w;
        union { unsigned u[4]; short8 v; } af;
        af.u[0] = pack2(r0, r1); af.u[1] = pack2(r2, r3);
        af.u[2] = pack2(r4, r5); af.u[3] = pack2(r6, r7);
        short8 bf = *(const short8*)(&uW.w[(tt * 64 + p) * 8]);
        acc = __builtin_amdgcn_mfma_f32_32x32x16_bf16(af.v, bf, acc, 0, 0, 0);
    }

    __syncthreads();                                   // (2) W dead -> overlay red
    if (par == 1) {                                    // odd waves spill
        #pragma unroll
        for (int r = 0; r < 16; ++r)
            uW.red[tile * 1024 + r * 64 + p] = acc[r];
    }
    __syncthreads();                                   // (3)
    if (par == 0) {                                    // even waves reduce + store
        // C/D layout: col(F) = lane&31, row = (r&3) + 8*(r>>2) + 4*(lane>>5)
        float bias = bg[p & 31];
        #pragma unroll
        for (int r = 0; r < 16; ++r) {
            float v = acc[r] + uW.red[tile * 1024 + r * 64 + p] + bias;
            int px = tile * 32 + (r & 3) + 8 * (r >> 2) + 4 * (p >> 5);
            int ho = oy + (px >> 3), wo = ox + (px & 7);
            if (ho < HO && wo < WO)
                out[(((size_t)bimg * HO + ho) * WO + wo) * F_OUT + (p & 31)] = v;
        }
    }
}

extern "C" void kernel_launch(void* const* d_in, const int* in_sizes, int n_in,
                              void* d_out, int out_size, void* d_ws, size_t ws_size,
                              hipStream_t stream) {
    const float* in = (const float*)d_in[0];
    const float* Wg = (const float*)d_in[1];
    const float* bg = (const float*)d_in[2];
    float* out      = (float*)d_out;
    dim3 grid((WO + TILE - 1) / TILE, (HO + TILE - 1) / TILE, NBATCH);
    rotconv_kernel<<<grid, dim3(BLOCK), 0, stream>>>(in, Wg, bg, out);
}